// Round 6
// baseline (365.118 us; speedup 1.0000x reference)
//
#include <hip/hip_runtime.h>
#include <hip/hip_fp16.h>

// Radon forward, parity-split LDS, image-pair half2 packing, vectorized fill,
// and (new this round) register ping-pong prefetch of the grid stream.
// x:   (2,1,256,256) fp32 ; all_grids: (180,363,363,2) fp32 ; circle = 0
// out: (2,1,363,180) fp32, out[n,0,w,l] = sum_r bilinear(pad(x), grid[l,r,w])
//
// Round-5 counters: dur 126.5us vs a ~35us max-pipe floor (VALU 35, LDS 28,
// HBM 31); VALUBusy 27.5% -> latency-exposed on the grid loads (loads and
// their consumers sit in the same loop iteration). Fix: double-buffer the
// 8-row grid batches in registers; issue batch k+1 before decoding batch k.

constexpr int W_IN   = 256;
constexpr int WP     = 363;
constexpr int L_ANG  = 180;
constexpr int NCHUNK = 4;
constexpr int CHUNK_LEN = 91;                 // 11*8 + 3 ; last chunk has 90 (masked)
constexpr int TOTAL  = L_ANG * NCHUNK * WP;   // 261360
constexpr int BLOCK  = 1024;
constexpr int RW     = 264;                   // cells/row: 4 zero | 256 data | 4 zero
constexpr int KROWS  = 130;                   // rows of one parity incl. borders
constexpr int CELLS  = RW * KROWS;            // 34320 uints = 137.3 KiB
constexpr int IMG_PIX = W_IN * W_IN;

__device__ __forceinline__ void fill_region(uint* __restrict__ xs,
                                            const float4* __restrict__ x0,
                                            const float4* __restrict__ x1,
                                            int parity) {
    // 66 uint4-groups per region row: g=0 left border, g=1..64 data, g=65 right border
    constexpr int GROUPS = KROWS * 66;        // 8580
    for (int i = threadIdx.x; i < GROUPS; i += BLOCK) {
        int k    = i / 66;
        int gcol = i - k * 66;
        int gr   = 2 * k - 2 + parity;        // global row: E -2..256, O -1..257
        uint4 val = {0u, 0u, 0u, 0u};
        if (((unsigned)gr < 256u) & (gcol >= 1) & (gcol <= 64)) {
            int fidx = (gr << 6) + (gcol - 1);
            float4 a = x0[fidx];
            float4 b = x1[fidx];
            val.x = __builtin_bit_cast(uint, __floats2half2_rn(a.x, b.x));
            val.y = __builtin_bit_cast(uint, __floats2half2_rn(a.y, b.y));
            val.z = __builtin_bit_cast(uint, __floats2half2_rn(a.z, b.z));
            val.w = __builtin_bit_cast(uint, __floats2half2_rn(a.w, b.w));
        }
        ((uint4*)xs)[i] = val;
    }
}

template <int P>
__device__ __forceinline__ void tap(const uint* __restrict__ xs, float2 gv, float ws,
                                    float& acc0, float& acc1) {
    // padded->original fold: gx_orig = (gv.x+1)*181 - 53 = gv.x*181 + 128
    float gx = fmaf(gv.x, 181.0f, 128.0f);
    float gy = fmaf(gv.y, 181.0f, 128.0f);
    gx = fminf(fmaxf(gx, -2.0f), 256.0f);     // clamp into zero-border range
    gy = fminf(fmaxf(gy, -2.0f), 256.0f);
    float fx = floorf(gx), fy = floorf(gy);
    float wx1 = gx - fx, wx0 = 1.0f - wx1;
    float wy1 = gy - fy;
    int ix = (int)fx;
    int iy = (int)fy;                         // -2..256
    int d  = (iy & 1) ^ P;                    // 0 -> row iy has parity P, 1 -> iy+1
    float wyp = (d ? wy1 : (1.0f - wy1)) * ws;
    int k    = ((iy + 1 - P) >> 1) + 1;       // region row holding the parity-P row
    int cell = k * RW + ix + 4;
    uint u0 = xs[cell];
    uint u1 = xs[cell + 1];
    float2 v0 = __half22float2(__builtin_bit_cast(__half2, u0));
    float2 v1 = __half22float2(__builtin_bit_cast(__half2, u1));
    float pa = wx0 * wyp, pb = wx1 * wyp;
    acc0 = fmaf(pa, v0.x, acc0);
    acc0 = fmaf(pb, v1.x, acc0);
    acc1 = fmaf(pa, v0.y, acc1);
    acc1 = fmaf(pb, v1.y, acc1);
}

__device__ __forceinline__ void load8(float2* dst, const float2* __restrict__ g,
                                      unsigned base) {
    #pragma unroll
    for (int u = 0; u < 8; ++u) dst[u] = g[base + u * WP];
}

template <int P>
__device__ __forceinline__ void tap8(const uint* __restrict__ xs, const float2* gv,
                                     float& a0, float& b0, float& a1, float& b1) {
    #pragma unroll
    for (int u = 0; u < 8; ++u) {
        if (u & 1) tap<P>(xs, gv[u], 1.0f, b0, b1);
        else       tap<P>(xs, gv[u], 1.0f, a0, a1);
    }
}

template <int P>
__device__ __forceinline__ void run_pass(const uint* __restrict__ xs,
                                         const float2* __restrict__ g,
                                         unsigned base, int r0,
                                         float& a0, float& b0,
                                         float& a1, float& b1) {
    float2 A[8], B[8];
    load8(A, g, base);                        // batch 0
    unsigned nb = base + 8u * WP;
    #pragma unroll
    for (int k = 0; k < 5; ++k) {
        load8(B, g, nb); nb += 8u * WP;       // issue batch 2k+1 loads...
        tap8<P>(xs, A, a0, b0, a1, b1);       // ...then decode batch 2k
        load8(A, g, nb); nb += 8u * WP;       // batch 2k+2
        tap8<P>(xs, B, a0, b0, a1, b1);       // batch 2k+1
    }
    // A holds batch 10 (rows r0+80..r0+87). Tail rows r0+88..r0+90 (masked):
    float2 T[3];
    #pragma unroll
    for (int u = 0; u < 3; ++u) {
        bool valid = (r0 + 88 + u) < WP;
        T[u] = g[valid ? (nb + (unsigned)(u * WP)) : 0u];
    }
    tap8<P>(xs, A, a0, b0, a1, b1);
    #pragma unroll
    for (int u = 0; u < 3; ++u) {
        float ws = ((r0 + 88 + u) < WP) ? 1.0f : 0.0f;
        if (u & 1) tap<P>(xs, T[u], ws, b0, b1);
        else       tap<P>(xs, T[u], ws, a0, a1);
    }
}

__global__ __launch_bounds__(BLOCK, 4) void radon_pp(
        const float*  __restrict__ x,     // (2,256,256)
        const float2* __restrict__ g,     // (180,363,363)
        float*        __restrict__ out) { // (2,363,180), pre-zeroed
    __shared__ uint xs[CELLS];            // 137.3 KiB

    int tid = blockIdx.x * BLOCK + threadIdx.x;
    bool active = tid < TOTAL;
    int t2 = active ? tid : 0;            // inactive threads duplicate work, skip store
    int w    = t2 % WP;
    int rest = t2 / WP;
    int chunk = rest % NCHUNK;
    int l     = rest / NCHUNK;
    int r0    = chunk * CHUNK_LEN;
    unsigned base = (unsigned)(l * WP + r0) * WP + (unsigned)w;

    float a0 = 0.0f, b0 = 0.0f, a1 = 0.0f, b1 = 0.0f;

    fill_region(xs, (const float4*)x, (const float4*)(x + IMG_PIX), 0);
    __syncthreads();
    run_pass<0>(xs, g, base, r0, a0, b0, a1, b1);
    __syncthreads();
    fill_region(xs, (const float4*)x, (const float4*)(x + IMG_PIX), 1);
    __syncthreads();
    run_pass<1>(xs, g, base, r0, a0, b0, a1, b1);

    if (active) {
        int o = w * L_ANG + l;            // out[n, w, l]
        atomicAdd(&out[o], a0 + b0);
        atomicAdd(&out[WP * L_ANG + o], a1 + b1);
    }
}

extern "C" void kernel_launch(void* const* d_in, const int* in_sizes, int n_in,
                              void* d_out, int out_size, void* d_ws, size_t ws_size,
                              hipStream_t stream) {
    const float*  x = (const float*)d_in[0];
    const float2* g = (const float2*)d_in[1];
    // d_in[2] is `circle` = 0 (compile-time assumption, matches setup_inputs)
    float* out = (float*)d_out;

    // d_out is re-poisoned (0xAA) before every timed replay -> zero it here.
    hipMemsetAsync(out, 0, (size_t)out_size * sizeof(float), stream);

    int blocks = (TOTAL + BLOCK - 1) / BLOCK;   // 256
    radon_pp<<<blocks, BLOCK, 0, stream>>>(x, g, out);
}